// Round 1
// baseline (424.406 us; speedup 1.0000x reference)
//
#include <hip/hip_runtime.h>
#include <hip/hip_bf16.h>
#include <stdint.h>

// Problem: B=2, S=4096, E=512, H=8, D=64.  All fp32 in/out; bf16 MFMA inside.
#define LOG2E 1.4426950408889634f

typedef __bf16 bf16;
typedef __bf16 bf16x8 __attribute__((ext_vector_type(8)));
typedef float  f32x4  __attribute__((ext_vector_type(4)));

__device__ __forceinline__ f32x4 mfma16(bf16x8 a, bf16x8 b, f32x4 c) {
    return __builtin_amdgcn_mfma_f32_16x16x32_bf16(a, b, c, 0, 0, 0);
}

// ---------------------------------------------------------------------------
// QKV GEMM: C[8192][1536] = X[8192][512] @ W[1536][512]^T + bias
// Epilogue routes: n<512 -> Q[bh][s][d], n<1024 -> K[bh][s][d], else V^T[bh][d][s]
// 128x128 tile, BK=64, 4 waves (2x2 of 64x64), XOR-swizzled LDS (16B chunks).
// ---------------------------------------------------------------------------
__global__ __launch_bounds__(256) void qkv_gemm_kernel(
    const float* __restrict__ X, const float* __restrict__ W,
    const float* __restrict__ bias,
    bf16* __restrict__ Qb, bf16* __restrict__ Kb, bf16* __restrict__ Vt)
{
    const int tid  = threadIdx.x;
    const int lane = tid & 63;
    const int wv   = tid >> 6;
    const int quad = lane >> 4;
    const int ln   = lane & 15;
    const int bm   = blockIdx.x;   // 64
    const int bn   = blockIdx.y;   // 12

    __shared__ __align__(16) bf16 As[128 * 64];
    __shared__ __align__(16) bf16 Bs[128 * 64];

    const int wm = (wv >> 1) * 64;
    const int wn = (wv & 1) * 64;

    f32x4 acc[4][4] = {};

    for (int kt = 0; kt < 512; kt += 64) {
        // stage A (fp32 -> bf16), 1024 16B chunks, swizzle cc ^= row&7
        #pragma unroll
        for (int i = 0; i < 4; ++i) {
            int c = tid + 256 * i;
            int row = c >> 3, cc = c & 7;
            const float* g = X + (size_t)(bm * 128 + row) * 512 + kt + cc * 8;
            float4 f0 = *(const float4*)g;
            float4 f1 = *(const float4*)(g + 4);
            bf16x8 v = { (bf16)f0.x,(bf16)f0.y,(bf16)f0.z,(bf16)f0.w,
                         (bf16)f1.x,(bf16)f1.y,(bf16)f1.z,(bf16)f1.w };
            *(bf16x8*)&As[(row * 8 + (cc ^ (row & 7))) * 8] = v;
        }
        #pragma unroll
        for (int i = 0; i < 4; ++i) {
            int c = tid + 256 * i;
            int row = c >> 3, cc = c & 7;
            const float* g = W + (size_t)(bn * 128 + row) * 512 + kt + cc * 8;
            float4 f0 = *(const float4*)g;
            float4 f1 = *(const float4*)(g + 4);
            bf16x8 v = { (bf16)f0.x,(bf16)f0.y,(bf16)f0.z,(bf16)f0.w,
                         (bf16)f1.x,(bf16)f1.y,(bf16)f1.z,(bf16)f1.w };
            *(bf16x8*)&Bs[(row * 8 + (cc ^ (row & 7))) * 8] = v;
        }
        __syncthreads();

        bf16x8 af[4][2], bfr[4][2];
        #pragma unroll
        for (int i = 0; i < 4; ++i) {
            #pragma unroll
            for (int c = 0; c < 2; ++c) {
                int ra = wm + i * 16 + ln;
                af[i][c]  = *(const bf16x8*)&As[(ra * 8 + ((c * 4 + quad) ^ (ra & 7))) * 8];
                int rb = wn + i * 16 + ln;
                bfr[i][c] = *(const bf16x8*)&Bs[(rb * 8 + ((c * 4 + quad) ^ (rb & 7))) * 8];
            }
        }
        #pragma unroll
        for (int c = 0; c < 2; ++c)
            #pragma unroll
            for (int i = 0; i < 4; ++i)
                #pragma unroll
                for (int j = 0; j < 4; ++j)
                    acc[i][j] = mfma16(af[i][c], bfr[j][c], acc[i][j]);
        __syncthreads();
    }

    // epilogue: C[m][n], lane holds rows quad*4+r, col ln of each 16x16 tile
    #pragma unroll
    for (int i = 0; i < 4; ++i) {
        int mbase = bm * 128 + wm + i * 16 + quad * 4;
        #pragma unroll
        for (int j = 0; j < 4; ++j) {
            int n = bn * 128 + wn + j * 16 + ln;
            float bv = bias[n];
            int sec = n >> 9;
            int e = n & 511;
            int hh = e >> 6, dd = e & 63;
            #pragma unroll
            for (int r = 0; r < 4; ++r) {
                int mm = mbase + r;
                int b = mm >> 12, s = mm & 4095;
                bf16 v = (bf16)(acc[i][j][r] + bv);
                size_t bhi = (size_t)(b * 8 + hh);
                if (sec == 0)      Qb[(bhi * 4096 + s) * 64 + dd] = v;
                else if (sec == 1) Kb[(bhi * 4096 + s) * 64 + dd] = v;
                else               Vt[(bhi * 64 + dd) * 4096 + s] = v;
            }
        }
    }
}

// ---------------------------------------------------------------------------
// Flash attention with Gaussian relative-position bias.
// Grid: (S/64, B*H). Block: 256 thr = 4 waves; wave w owns q rows w*16..w*16+15.
// ---------------------------------------------------------------------------
__global__ __launch_bounds__(256) void attn_kernel(
    const bf16* __restrict__ Qb, const bf16* __restrict__ Kb,
    const bf16* __restrict__ Vt, const float* __restrict__ T,
    bf16* __restrict__ AO)
{
    const int tid  = threadIdx.x;
    const int lane = tid & 63;
    const int wv   = tid >> 6;
    const int quad = lane >> 4;
    const int ln   = lane & 15;
    const int qt   = blockIdx.x;   // 64
    const int bh   = blockIdx.y;   // 16
    const int h    = bh & 7;
    const int b    = bh >> 3;

    __shared__ __align__(16) bf16 Ks[64 * 64];
    __shared__ __align__(16) bf16 Vs[64 * 64];   // V^T tile: [d][k]
    __shared__ __align__(16) bf16 Ps[4][16 * 64];

    const float t  = T[h];
    const float s2 = t * t;
    const float cb = 1.0f / (2.0f * s2 * s2);    // bias = -dist2 * cb

    // Q A-operand fragments (m = lane&15, k = quad*8+j, two 32-k chunks)
    const int qrow_f = qt * 64 + wv * 16 + ln;
    const bf16* qptr = Qb + ((size_t)bh * 4096 + qrow_f) * 64 + quad * 8;
    bf16x8 qf0 = *(const bf16x8*)qptr;
    bf16x8 qf1 = *(const bf16x8*)(qptr + 32);

    const int qrow_c = qt * 64 + wv * 16 + quad * 4;   // C-layout row base

    float m_i[4], l_i[4];
    f32x4 o[4] = {};
    #pragma unroll
    for (int r = 0; r < 4; ++r) { m_i[r] = -1e30f; l_i[r] = 0.0f; }

    for (int kt = 0; kt < 4096; kt += 64) {
        // stage K tile [k][d] and V^T tile [d][k], swizzled
        #pragma unroll
        for (int i = 0; i < 2; ++i) {
            int c = tid + 256 * i;
            int row = c >> 3, cc = c & 7;
            uint4 kv = *(const uint4*)&Kb[((size_t)bh * 4096 + kt + row) * 64 + cc * 8];
            *(uint4*)&Ks[(row * 8 + (cc ^ (row & 7))) * 8] = kv;
            uint4 vv = *(const uint4*)&Vt[((size_t)bh * 64 + row) * 4096 + kt + cc * 8];
            *(uint4*)&Vs[(row * 8 + (cc ^ (row & 7))) * 8] = vv;
        }
        __syncthreads();

        // S = Q K^T  (16 q-rows x 64 k-cols)
        f32x4 sc[4] = {};
        #pragma unroll
        for (int tI = 0; tI < 4; ++tI) {
            int row = tI * 16 + ln;
            bf16x8 kf0 = *(const bf16x8*)&Ks[(row * 8 + ((quad    ) ^ (row & 7))) * 8];
            bf16x8 kf1 = *(const bf16x8*)&Ks[(row * 8 + ((4 + quad) ^ (row & 7))) * 8];
            sc[tI] = mfma16(qf0, kf0, sc[tI]);
            sc[tI] = mfma16(qf1, kf1, sc[tI]);
        }

        // online softmax (rows quad*4+r; 16 lanes of each quad share a row)
        float p[4][4], alpha[4];
        #pragma unroll
        for (int r = 0; r < 4; ++r) {
            float qi = (float)(qrow_c + r);
            float mx = -3.0e38f;
            #pragma unroll
            for (int tI = 0; tI < 4; ++tI) {
                float kj = (float)(kt + tI * 16 + ln);
                float df = qi - kj;
                float lg = sc[tI][r] * 0.125f - df * df * cb;
                p[tI][r] = lg;
                mx = fmaxf(mx, lg);
            }
            #pragma unroll
            for (int off = 1; off < 16; off <<= 1)
                mx = fmaxf(mx, __shfl_xor(mx, off));
            float mn = fmaxf(m_i[r], mx);
            alpha[r] = __builtin_amdgcn_exp2f((m_i[r] - mn) * LOG2E);
            float srow = 0.0f;
            #pragma unroll
            for (int tI = 0; tI < 4; ++tI) {
                float pv = __builtin_amdgcn_exp2f((p[tI][r] - mn) * LOG2E);
                p[tI][r] = pv;
                srow += pv;
            }
            #pragma unroll
            for (int off = 1; off < 16; off <<= 1)
                srow += __shfl_xor(srow, off);
            l_i[r] = l_i[r] * alpha[r] + srow;
            m_i[r] = mn;
        }
        #pragma unroll
        for (int t2 = 0; t2 < 4; ++t2)
            #pragma unroll
            for (int r = 0; r < 4; ++r)
                o[t2][r] *= alpha[r];

        // P (C-layout) -> LDS -> A-operand layout; wave-private, no barrier
        #pragma unroll
        for (int tI = 0; tI < 4; ++tI)
            #pragma unroll
            for (int r = 0; r < 4; ++r) {
                int row = quad * 4 + r;
                int cc  = tI * 2 + (ln >> 3);
                int idx = row * 64 + ((cc ^ (row & 7)) * 8) + (ln & 7);
                Ps[wv][idx] = (bf16)p[tI][r];
            }

        bf16x8 pf[2];
        #pragma unroll
        for (int c = 0; c < 2; ++c)
            pf[c] = *(const bf16x8*)&Ps[wv][(ln * 8 + ((c * 4 + quad) ^ (ln & 7))) * 8];

        // O += P V   (V^T tile gives B-operand: n=d=lane&15 row, k contiguous)
        #pragma unroll
        for (int t2 = 0; t2 < 4; ++t2) {
            int vrow = t2 * 16 + ln;
            #pragma unroll
            for (int c = 0; c < 2; ++c) {
                bf16x8 vf = *(const bf16x8*)&Vs[(vrow * 8 + ((c * 4 + quad) ^ (vrow & 7))) * 8];
                o[t2] = mfma16(pf[c], vf, o[t2]);
            }
        }
        __syncthreads();
    }

    // epilogue: out[s][h*64+d] = O / l
    float il[4];
    #pragma unroll
    for (int r = 0; r < 4; ++r) il[r] = __builtin_amdgcn_rcpf(l_i[r]);
    #pragma unroll
    for (int t2 = 0; t2 < 4; ++t2) {
        int dd = t2 * 16 + ln;
        #pragma unroll
        for (int r = 0; r < 4; ++r) {
            int s = qt * 64 + wv * 16 + quad * 4 + r;
            AO[((size_t)(b * 4096 + s)) * 512 + h * 64 + dd] = (bf16)(o[t2][r] * il[r]);
        }
    }
}

// ---------------------------------------------------------------------------
// Out projection: OUT[8192][512] = AO[8192][512](bf16) @ W[512][512]^T + bias
// ---------------------------------------------------------------------------
__global__ __launch_bounds__(256) void out_gemm_kernel(
    const bf16* __restrict__ A, const float* __restrict__ W,
    const float* __restrict__ bias, float* __restrict__ OUT)
{
    const int tid  = threadIdx.x;
    const int lane = tid & 63;
    const int wv   = tid >> 6;
    const int quad = lane >> 4;
    const int ln   = lane & 15;
    const int bm   = blockIdx.x;   // 64
    const int bn   = blockIdx.y;   // 4

    __shared__ __align__(16) bf16 As[128 * 64];
    __shared__ __align__(16) bf16 Bs[128 * 64];

    const int wm = (wv >> 1) * 64;
    const int wn = (wv & 1) * 64;

    f32x4 acc[4][4] = {};

    for (int kt = 0; kt < 512; kt += 64) {
        #pragma unroll
        for (int i = 0; i < 4; ++i) {
            int c = tid + 256 * i;
            int row = c >> 3, cc = c & 7;
            uint4 v = *(const uint4*)&A[(size_t)(bm * 128 + row) * 512 + kt + cc * 8];
            *(uint4*)&As[(row * 8 + (cc ^ (row & 7))) * 8] = v;
        }
        #pragma unroll
        for (int i = 0; i < 4; ++i) {
            int c = tid + 256 * i;
            int row = c >> 3, cc = c & 7;
            const float* g = W + (size_t)(bn * 128 + row) * 512 + kt + cc * 8;
            float4 f0 = *(const float4*)g;
            float4 f1 = *(const float4*)(g + 4);
            bf16x8 v = { (bf16)f0.x,(bf16)f0.y,(bf16)f0.z,(bf16)f0.w,
                         (bf16)f1.x,(bf16)f1.y,(bf16)f1.z,(bf16)f1.w };
            *(bf16x8*)&Bs[(row * 8 + (cc ^ (row & 7))) * 8] = v;
        }
        __syncthreads();

        bf16x8 af[4][2], bfr[4][2];
        #pragma unroll
        for (int i = 0; i < 4; ++i) {
            #pragma unroll
            for (int c = 0; c < 2; ++c) {
                int ra = wm + i * 16 + ln;
                af[i][c]  = *(const bf16x8*)&As[(ra * 8 + ((c * 4 + quad) ^ (ra & 7))) * 8];
                int rb = wn + i * 16 + ln;
                bfr[i][c] = *(const bf16x8*)&Bs[(rb * 8 + ((c * 4 + quad) ^ (rb & 7))) * 8];
            }
        }
        #pragma unroll
        for (int c = 0; c < 2; ++c)
            #pragma unroll
            for (int i = 0; i < 4; ++i)
                #pragma unroll
                for (int j = 0; j < 4; ++j)
                    acc[i][j] = mfma16(af[i][c], bfr[j][c], acc[i][j]);
        __syncthreads();
    }

    #pragma unroll
    for (int i = 0; i < 4; ++i) {
        int mbase = bm * 128 + wm + i * 16 + quad * 4;
        #pragma unroll
        for (int j = 0; j < 4; ++j) {
            int n = bn * 128 + wn + j * 16 + ln;
            float bv = bias[n];
            #pragma unroll
            for (int r = 0; r < 4; ++r)
                OUT[(size_t)(mbase + r) * 512 + n] = acc[i][j][r] + bv;
        }
    }
}

extern "C" void kernel_launch(void* const* d_in, const int* in_sizes, int n_in,
                              void* d_out, int out_size, void* d_ws, size_t ws_size,
                              hipStream_t stream)
{
    const float* x  = (const float*)d_in[0];
    const float* wi = (const float*)d_in[1];
    const float* bi = (const float*)d_in[2];
    const float* wo = (const float*)d_in[3];
    const float* bo = (const float*)d_in[4];
    const float* t  = (const float*)d_in[5];
    float* out = (float*)d_out;

    // ws layout: Q, K, V^T, attn_out  — each [16][4096][64] bf16 = 8 MB
    bf16* Qb = (bf16*)d_ws;
    bf16* Kb = Qb + 4194304;
    bf16* Vt = Kb + 4194304;
    bf16* AO = Vt + 4194304;

    qkv_gemm_kernel<<<dim3(64, 12), 256, 0, stream>>>(x, wi, bi, Qb, Kb, Vt);
    attn_kernel   <<<dim3(64, 16), 256, 0, stream>>>(Qb, Kb, Vt, t, AO);
    out_gemm_kernel<<<dim3(64, 4), 256, 0, stream>>>(AO, wo, bo, out);
}

// Round 2
// 145.726 us; speedup vs baseline: 2.9123x; 2.9123x over previous
//
#include <hip/hip_runtime.h>
#include <hip/hip_bf16.h>
#include <stdint.h>

// Problem: B=2, S=4096, E=512, H=8, D=64.  All fp32 in/out; bf16 MFMA inside.
#define LOG2E 1.4426950408889634f

typedef __bf16 bf16;
typedef __bf16 bf16x8 __attribute__((ext_vector_type(8)));
typedef float  f32x4  __attribute__((ext_vector_type(4)));

__device__ __forceinline__ f32x4 mfma16(bf16x8 a, bf16x8 b, f32x4 c) {
    return __builtin_amdgcn_mfma_f32_16x16x32_bf16(a, b, c, 0, 0, 0);
}

// ---------------------------------------------------------------------------
// QKV GEMM: C[8192][1536] = X[8192][512] @ W[1536][512]^T + bias
// Epilogue routes: n<512 -> Q[bh][s][d], n<1024 -> K[bh][s][d], else V^T[bh][d][s]
// 128x128 tile, BK=64, 4 waves (2x2 of 64x64), XOR-swizzled LDS (16B chunks).
// ---------------------------------------------------------------------------
__global__ __launch_bounds__(256) void qkv_gemm_kernel(
    const float* __restrict__ X, const float* __restrict__ W,
    const float* __restrict__ bias,
    bf16* __restrict__ Qb, bf16* __restrict__ Kb, bf16* __restrict__ Vt)
{
    const int tid  = threadIdx.x;
    const int lane = tid & 63;
    const int wv   = tid >> 6;
    const int quad = lane >> 4;
    const int ln   = lane & 15;
    const int bm   = blockIdx.x;   // 64
    const int bn   = blockIdx.y;   // 12

    __shared__ __align__(16) bf16 As[128 * 64];
    __shared__ __align__(16) bf16 Bs[128 * 64];

    const int wm = (wv >> 1) * 64;
    const int wn = (wv & 1) * 64;

    f32x4 acc[4][4] = {};

    for (int kt = 0; kt < 512; kt += 64) {
        // stage A (fp32 -> bf16), 1024 16B chunks, swizzle cc ^= row&7
        #pragma unroll
        for (int i = 0; i < 4; ++i) {
            int c = tid + 256 * i;
            int row = c >> 3, cc = c & 7;
            const float* g = X + (size_t)(bm * 128 + row) * 512 + kt + cc * 8;
            float4 f0 = *(const float4*)g;
            float4 f1 = *(const float4*)(g + 4);
            bf16x8 v = { (bf16)f0.x,(bf16)f0.y,(bf16)f0.z,(bf16)f0.w,
                         (bf16)f1.x,(bf16)f1.y,(bf16)f1.z,(bf16)f1.w };
            *(bf16x8*)&As[(row * 8 + (cc ^ (row & 7))) * 8] = v;
        }
        #pragma unroll
        for (int i = 0; i < 4; ++i) {
            int c = tid + 256 * i;
            int row = c >> 3, cc = c & 7;
            const float* g = W + (size_t)(bn * 128 + row) * 512 + kt + cc * 8;
            float4 f0 = *(const float4*)g;
            float4 f1 = *(const float4*)(g + 4);
            bf16x8 v = { (bf16)f0.x,(bf16)f0.y,(bf16)f0.z,(bf16)f0.w,
                         (bf16)f1.x,(bf16)f1.y,(bf16)f1.z,(bf16)f1.w };
            *(bf16x8*)&Bs[(row * 8 + (cc ^ (row & 7))) * 8] = v;
        }
        __syncthreads();

        bf16x8 af[4][2], bfr[4][2];
        #pragma unroll
        for (int i = 0; i < 4; ++i) {
            #pragma unroll
            for (int c = 0; c < 2; ++c) {
                int ra = wm + i * 16 + ln;
                af[i][c]  = *(const bf16x8*)&As[(ra * 8 + ((c * 4 + quad) ^ (ra & 7))) * 8];
                int rb = wn + i * 16 + ln;
                bfr[i][c] = *(const bf16x8*)&Bs[(rb * 8 + ((c * 4 + quad) ^ (rb & 7))) * 8];
            }
        }
        #pragma unroll
        for (int c = 0; c < 2; ++c)
            #pragma unroll
            for (int i = 0; i < 4; ++i)
                #pragma unroll
                for (int j = 0; j < 4; ++j)
                    acc[i][j] = mfma16(af[i][c], bfr[j][c], acc[i][j]);
        __syncthreads();
    }

    // epilogue: C[m][n], lane holds rows quad*4+r, col ln of each 16x16 tile
    #pragma unroll
    for (int i = 0; i < 4; ++i) {
        int mbase = bm * 128 + wm + i * 16 + quad * 4;
        #pragma unroll
        for (int j = 0; j < 4; ++j) {
            int n = bn * 128 + wn + j * 16 + ln;
            float bv = bias[n];
            int sec = n >> 9;
            int e = n & 511;
            int hh = e >> 6, dd = e & 63;
            #pragma unroll
            for (int r = 0; r < 4; ++r) {
                int mm = mbase + r;
                int b = mm >> 12, s = mm & 4095;
                bf16 v = (bf16)(acc[i][j][r] + bv);
                size_t bhi = (size_t)(b * 8 + hh);
                if (sec == 0)      Qb[(bhi * 4096 + s) * 64 + dd] = v;
                else if (sec == 1) Kb[(bhi * 4096 + s) * 64 + dd] = v;
                else               Vt[(bhi * 64 + dd) * 4096 + s] = v;
            }
        }
    }
}

// ---------------------------------------------------------------------------
// Flash attention with Gaussian relative-position bias — BANDED.
// bias = -(q-k)^2/(2 t^4): for |q-k| > R = t^2*sqrt(180) the softmax weight
// is < exp(-80) relative to the row max (scores bounded ~|6|), i.e. zero at
// bf16 precision. Iterate only k-tiles inside the band.
// Grid: (S/64, B*H). Block: 256 thr = 4 waves; wave w owns q rows w*16..+15.
// ---------------------------------------------------------------------------
__global__ __launch_bounds__(256) void attn_kernel(
    const bf16* __restrict__ Qb, const bf16* __restrict__ Kb,
    const bf16* __restrict__ Vt, const float* __restrict__ T,
    bf16* __restrict__ AO)
{
    const int tid  = threadIdx.x;
    const int lane = tid & 63;
    const int wv   = tid >> 6;
    const int quad = lane >> 4;
    const int ln   = lane & 15;
    const int qt   = blockIdx.x;   // 64
    const int bh   = blockIdx.y;   // 16
    const int h    = bh & 7;
    const int b    = bh >> 3;

    __shared__ __align__(16) bf16 Ks[64 * 64];
    __shared__ __align__(16) bf16 Vs[64 * 64];   // V^T tile: [d][k]
    __shared__ __align__(16) bf16 Ps[4][16 * 64];

    const float t  = T[h];
    const float s2 = t * t;
    const float cb = 1.0f / (2.0f * s2 * s2);    // bias = -dist2 * cb

    // band radius: dist^2 * cb >= 90  =>  dist >= t^2 * sqrt(180)
    const int R  = (int)ceilf(s2 * 13.4164f) + 1;
    int lo = qt * 64 - R;      if (lo < 0) lo = 0;     lo &= ~63;
    int hi = qt * 64 + 64 + R; if (hi > 4096) hi = 4096; hi = (hi + 63) & ~63;

    // Q A-operand fragments (m = lane&15, k = quad*8+j, two 32-k chunks)
    const int qrow_f = qt * 64 + wv * 16 + ln;
    const bf16* qptr = Qb + ((size_t)bh * 4096 + qrow_f) * 64 + quad * 8;
    bf16x8 qf0 = *(const bf16x8*)qptr;
    bf16x8 qf1 = *(const bf16x8*)(qptr + 32);

    const int qrow_c = qt * 64 + wv * 16 + quad * 4;   // C-layout row base

    float m_i[4], l_i[4];
    f32x4 o[4] = {};
    #pragma unroll
    for (int r = 0; r < 4; ++r) { m_i[r] = -1e30f; l_i[r] = 0.0f; }

    for (int kt = lo; kt < hi; kt += 64) {
        // stage K tile [k][d] and V^T tile [d][k], swizzled
        #pragma unroll
        for (int i = 0; i < 2; ++i) {
            int c = tid + 256 * i;
            int row = c >> 3, cc = c & 7;
            uint4 kv = *(const uint4*)&Kb[((size_t)bh * 4096 + kt + row) * 64 + cc * 8];
            *(uint4*)&Ks[(row * 8 + (cc ^ (row & 7))) * 8] = kv;
            uint4 vv = *(const uint4*)&Vt[((size_t)bh * 64 + row) * 4096 + kt + cc * 8];
            *(uint4*)&Vs[(row * 8 + (cc ^ (row & 7))) * 8] = vv;
        }
        __syncthreads();

        // S = Q K^T  (16 q-rows x 64 k-cols)
        f32x4 sc[4] = {};
        #pragma unroll
        for (int tI = 0; tI < 4; ++tI) {
            int row = tI * 16 + ln;
            bf16x8 kf0 = *(const bf16x8*)&Ks[(row * 8 + ((quad    ) ^ (row & 7))) * 8];
            bf16x8 kf1 = *(const bf16x8*)&Ks[(row * 8 + ((4 + quad) ^ (row & 7))) * 8];
            sc[tI] = mfma16(qf0, kf0, sc[tI]);
            sc[tI] = mfma16(qf1, kf1, sc[tI]);
        }

        // online softmax (rows quad*4+r; 16 lanes of each quad share a row)
        float p[4][4], alpha[4];
        #pragma unroll
        for (int r = 0; r < 4; ++r) {
            float qi = (float)(qrow_c + r);
            float mx = -3.0e38f;
            #pragma unroll
            for (int tI = 0; tI < 4; ++tI) {
                float kj = (float)(kt + tI * 16 + ln);
                float df = qi - kj;
                float lg = sc[tI][r] * 0.125f - df * df * cb;
                p[tI][r] = lg;
                mx = fmaxf(mx, lg);
            }
            #pragma unroll
            for (int off = 1; off < 16; off <<= 1)
                mx = fmaxf(mx, __shfl_xor(mx, off));
            float mn = fmaxf(m_i[r], mx);
            alpha[r] = __builtin_amdgcn_exp2f((m_i[r] - mn) * LOG2E);
            float srow = 0.0f;
            #pragma unroll
            for (int tI = 0; tI < 4; ++tI) {
                float pv = __builtin_amdgcn_exp2f((p[tI][r] - mn) * LOG2E);
                p[tI][r] = pv;
                srow += pv;
            }
            #pragma unroll
            for (int off = 1; off < 16; off <<= 1)
                srow += __shfl_xor(srow, off);
            l_i[r] = l_i[r] * alpha[r] + srow;
            m_i[r] = mn;
        }
        #pragma unroll
        for (int t2 = 0; t2 < 4; ++t2)
            #pragma unroll
            for (int r = 0; r < 4; ++r)
                o[t2][r] *= alpha[r];

        // P (C-layout) -> LDS -> A-operand layout; wave-private, no barrier
        #pragma unroll
        for (int tI = 0; tI < 4; ++tI)
            #pragma unroll
            for (int r = 0; r < 4; ++r) {
                int row = quad * 4 + r;
                int cc  = tI * 2 + (ln >> 3);
                int idx = row * 64 + ((cc ^ (row & 7)) * 8) + (ln & 7);
                Ps[wv][idx] = (bf16)p[tI][r];
            }

        bf16x8 pf[2];
        #pragma unroll
        for (int c = 0; c < 2; ++c)
            pf[c] = *(const bf16x8*)&Ps[wv][(ln * 8 + ((c * 4 + quad) ^ (ln & 7))) * 8];

        // O += P V   (V^T tile gives B-operand: n=d=lane&15 row, k contiguous)
        #pragma unroll
        for (int t2 = 0; t2 < 4; ++t2) {
            int vrow = t2 * 16 + ln;
            #pragma unroll
            for (int c = 0; c < 2; ++c) {
                bf16x8 vf = *(const bf16x8*)&Vs[(vrow * 8 + ((c * 4 + quad) ^ (vrow & 7))) * 8];
                o[t2] = mfma16(pf[c], vf, o[t2]);
            }
        }
        __syncthreads();
    }

    // epilogue: out[s][h*64+d] = O / l
    float il[4];
    #pragma unroll
    for (int r = 0; r < 4; ++r) il[r] = __builtin_amdgcn_rcpf(l_i[r]);
    #pragma unroll
    for (int t2 = 0; t2 < 4; ++t2) {
        int dd = t2 * 16 + ln;
        #pragma unroll
        for (int r = 0; r < 4; ++r) {
            int s = qt * 64 + wv * 16 + quad * 4 + r;
            AO[((size_t)(b * 4096 + s)) * 512 + h * 64 + dd] = (bf16)(o[t2][r] * il[r]);
        }
    }
}

// ---------------------------------------------------------------------------
// Out projection: OUT[8192][512] = AO[8192][512](bf16) @ W[512][512]^T + bias
// ---------------------------------------------------------------------------
__global__ __launch_bounds__(256) void out_gemm_kernel(
    const bf16* __restrict__ A, const float* __restrict__ W,
    const float* __restrict__ bias, float* __restrict__ OUT)
{
    const int tid  = threadIdx.x;
    const int lane = tid & 63;
    const int wv   = tid >> 6;
    const int quad = lane >> 4;
    const int ln   = lane & 15;
    const int bm   = blockIdx.x;   // 64
    const int bn   = blockIdx.y;   // 4

    __shared__ __align__(16) bf16 As[128 * 64];
    __shared__ __align__(16) bf16 Bs[128 * 64];

    const int wm = (wv >> 1) * 64;
    const int wn = (wv & 1) * 64;

    f32x4 acc[4][4] = {};

    for (int kt = 0; kt < 512; kt += 64) {
        #pragma unroll
        for (int i = 0; i < 4; ++i) {
            int c = tid + 256 * i;
            int row = c >> 3, cc = c & 7;
            uint4 v = *(const uint4*)&A[(size_t)(bm * 128 + row) * 512 + kt + cc * 8];
            *(uint4*)&As[(row * 8 + (cc ^ (row & 7))) * 8] = v;
        }
        #pragma unroll
        for (int i = 0; i < 4; ++i) {
            int c = tid + 256 * i;
            int row = c >> 3, cc = c & 7;
            const float* g = W + (size_t)(bn * 128 + row) * 512 + kt + cc * 8;
            float4 f0 = *(const float4*)g;
            float4 f1 = *(const float4*)(g + 4);
            bf16x8 v = { (bf16)f0.x,(bf16)f0.y,(bf16)f0.z,(bf16)f0.w,
                         (bf16)f1.x,(bf16)f1.y,(bf16)f1.z,(bf16)f1.w };
            *(bf16x8*)&Bs[(row * 8 + (cc ^ (row & 7))) * 8] = v;
        }
        __syncthreads();

        bf16x8 af[4][2], bfr[4][2];
        #pragma unroll
        for (int i = 0; i < 4; ++i) {
            #pragma unroll
            for (int c = 0; c < 2; ++c) {
                int ra = wm + i * 16 + ln;
                af[i][c]  = *(const bf16x8*)&As[(ra * 8 + ((c * 4 + quad) ^ (ra & 7))) * 8];
                int rb = wn + i * 16 + ln;
                bfr[i][c] = *(const bf16x8*)&Bs[(rb * 8 + ((c * 4 + quad) ^ (rb & 7))) * 8];
            }
        }
        #pragma unroll
        for (int c = 0; c < 2; ++c)
            #pragma unroll
            for (int i = 0; i < 4; ++i)
                #pragma unroll
                for (int j = 0; j < 4; ++j)
                    acc[i][j] = mfma16(af[i][c], bfr[j][c], acc[i][j]);
        __syncthreads();
    }

    #pragma unroll
    for (int i = 0; i < 4; ++i) {
        int mbase = bm * 128 + wm + i * 16 + quad * 4;
        #pragma unroll
        for (int j = 0; j < 4; ++j) {
            int n = bn * 128 + wn + j * 16 + ln;
            float bv = bias[n];
            #pragma unroll
            for (int r = 0; r < 4; ++r)
                OUT[(size_t)(mbase + r) * 512 + n] = acc[i][j][r] + bv;
        }
    }
}

extern "C" void kernel_launch(void* const* d_in, const int* in_sizes, int n_in,
                              void* d_out, int out_size, void* d_ws, size_t ws_size,
                              hipStream_t stream)
{
    const float* x  = (const float*)d_in[0];
    const float* wi = (const float*)d_in[1];
    const float* bi = (const float*)d_in[2];
    const float* wo = (const float*)d_in[3];
    const float* bo = (const float*)d_in[4];
    const float* t  = (const float*)d_in[5];
    float* out = (float*)d_out;

    // ws layout: Q, K, V^T, attn_out  — each [16][4096][64] bf16 = 8 MB
    bf16* Qb = (bf16*)d_ws;
    bf16* Kb = Qb + 4194304;
    bf16* Vt = Kb + 4194304;
    bf16* AO = Vt + 4194304;

    qkv_gemm_kernel<<<dim3(64, 12), 256, 0, stream>>>(x, wi, bi, Qb, Kb, Vt);
    attn_kernel   <<<dim3(64, 16), 256, 0, stream>>>(Qb, Kb, Vt, t, AO);
    out_gemm_kernel<<<dim3(64, 4), 256, 0, stream>>>(AO, wo, bo, out);
}

// Round 3
// 138.974 us; speedup vs baseline: 3.0539x; 1.0486x over previous
//
#include <hip/hip_runtime.h>
#include <hip/hip_bf16.h>
#include <stdint.h>

// Problem: B=2, S=4096, E=512, H=8, D=64.  All fp32 in/out; bf16 MFMA inside.
#define LOG2E 1.4426950408889634f

typedef __bf16 bf16;
typedef __bf16 bf16x8 __attribute__((ext_vector_type(8)));
typedef float  f32x4  __attribute__((ext_vector_type(4)));

__device__ __forceinline__ f32x4 mfma16(bf16x8 a, bf16x8 b, f32x4 c) {
    return __builtin_amdgcn_mfma_f32_16x16x32_bf16(a, b, c, 0, 0, 0);
}

__device__ __forceinline__ void async16(const void* g, void* l) {
    __builtin_amdgcn_global_load_lds(
        (const __attribute__((address_space(1))) void*)g,
        (__attribute__((address_space(3))) void*)l, 16, 0, 0);
}

// ---------------------------------------------------------------------------
// QKV GEMM: C[8192][1536] = X[8192][512] @ W[1536][512]^T + bias
// Epilogue routes: n<512 -> Q[bh][s][d], n<1024 -> K[bh][s][d], else V^T[bh][d][s]
// 128x128 tile, BK=64, 4 waves (2x2 of 64x64), XOR-swizzled LDS (16B chunks).
// ---------------------------------------------------------------------------
__global__ __launch_bounds__(256) void qkv_gemm_kernel(
    const float* __restrict__ X, const float* __restrict__ W,
    const float* __restrict__ bias,
    bf16* __restrict__ Qb, bf16* __restrict__ Kb, bf16* __restrict__ Vt)
{
    const int tid  = threadIdx.x;
    const int lane = tid & 63;
    const int wv   = tid >> 6;
    const int quad = lane >> 4;
    const int ln   = lane & 15;
    const int bm   = blockIdx.x;   // 64
    const int bn   = blockIdx.y;   // 12

    __shared__ __align__(16) bf16 As[128 * 64];
    __shared__ __align__(16) bf16 Bs[128 * 64];

    const int wm = (wv >> 1) * 64;
    const int wn = (wv & 1) * 64;

    f32x4 acc[4][4] = {};

    for (int kt = 0; kt < 512; kt += 64) {
        #pragma unroll
        for (int i = 0; i < 4; ++i) {
            int c = tid + 256 * i;
            int row = c >> 3, cc = c & 7;
            const float* g = X + (size_t)(bm * 128 + row) * 512 + kt + cc * 8;
            float4 f0 = *(const float4*)g;
            float4 f1 = *(const float4*)(g + 4);
            bf16x8 v = { (bf16)f0.x,(bf16)f0.y,(bf16)f0.z,(bf16)f0.w,
                         (bf16)f1.x,(bf16)f1.y,(bf16)f1.z,(bf16)f1.w };
            *(bf16x8*)&As[(row * 8 + (cc ^ (row & 7))) * 8] = v;
        }
        #pragma unroll
        for (int i = 0; i < 4; ++i) {
            int c = tid + 256 * i;
            int row = c >> 3, cc = c & 7;
            const float* g = W + (size_t)(bn * 128 + row) * 512 + kt + cc * 8;
            float4 f0 = *(const float4*)g;
            float4 f1 = *(const float4*)(g + 4);
            bf16x8 v = { (bf16)f0.x,(bf16)f0.y,(bf16)f0.z,(bf16)f0.w,
                         (bf16)f1.x,(bf16)f1.y,(bf16)f1.z,(bf16)f1.w };
            *(bf16x8*)&Bs[(row * 8 + (cc ^ (row & 7))) * 8] = v;
        }
        __syncthreads();

        bf16x8 af[4][2], bfr[4][2];
        #pragma unroll
        for (int i = 0; i < 4; ++i) {
            #pragma unroll
            for (int c = 0; c < 2; ++c) {
                int ra = wm + i * 16 + ln;
                af[i][c]  = *(const bf16x8*)&As[(ra * 8 + ((c * 4 + quad) ^ (ra & 7))) * 8];
                int rb = wn + i * 16 + ln;
                bfr[i][c] = *(const bf16x8*)&Bs[(rb * 8 + ((c * 4 + quad) ^ (rb & 7))) * 8];
            }
        }
        #pragma unroll
        for (int c = 0; c < 2; ++c)
            #pragma unroll
            for (int i = 0; i < 4; ++i)
                #pragma unroll
                for (int j = 0; j < 4; ++j)
                    acc[i][j] = mfma16(af[i][c], bfr[j][c], acc[i][j]);
        __syncthreads();
    }

    #pragma unroll
    for (int i = 0; i < 4; ++i) {
        int mbase = bm * 128 + wm + i * 16 + quad * 4;
        #pragma unroll
        for (int j = 0; j < 4; ++j) {
            int n = bn * 128 + wn + j * 16 + ln;
            float bv = bias[n];
            int sec = n >> 9;
            int e = n & 511;
            int hh = e >> 6, dd = e & 63;
            #pragma unroll
            for (int r = 0; r < 4; ++r) {
                int mm = mbase + r;
                int b = mm >> 12, s = mm & 4095;
                bf16 v = (bf16)(acc[i][j][r] + bv);
                size_t bhi = (size_t)(b * 8 + hh);
                if (sec == 0)      Qb[(bhi * 4096 + s) * 64 + dd] = v;
                else if (sec == 1) Kb[(bhi * 4096 + s) * 64 + dd] = v;
                else               Vt[(bhi * 64 + dd) * 4096 + s] = v;
            }
        }
    }
}

// ---------------------------------------------------------------------------
// Flash attention, BANDED, fixed-max softmax (no rescale), l via ones-MFMA.
// Chunked async staging: 2 k-tiles per chunk via global_load_lds width=16,
// swizzle applied on the GLOBAL source address (LDS dest = base + lane*16).
// Grid: (S/64, B*H). Block: 256 thr = 4 waves; wave w owns q rows w*16..+15.
// ---------------------------------------------------------------------------
__global__ __launch_bounds__(256) void attn_kernel(
    const bf16* __restrict__ Qb, const bf16* __restrict__ Kb,
    const bf16* __restrict__ Vt, const float* __restrict__ T,
    bf16* __restrict__ AO)
{
    const int tid  = threadIdx.x;
    const int lane = tid & 63;
    const int wv   = tid >> 6;
    const int quad = lane >> 4;
    const int ln   = lane & 15;
    const int qt   = blockIdx.x;   // 64
    const int bh   = blockIdx.y;   // 16
    const int h    = bh & 7;
    const int b    = bh >> 3;

    // [tile 0/1][K=0,V=1][64*64]
    __shared__ __align__(16) bf16 KVs[2][2][64 * 64];
    __shared__ __align__(16) bf16 Ps[4][16 * 64];

    const float t  = T[h];
    const float s2 = t * t;
    const float cb = 1.0f / (2.0f * s2 * s2);    // bias = -dist2 * cb

    // band radius: dist^2 * cb >= 90  =>  dist >= t^2 * sqrt(180)
    const int R  = (int)ceilf(s2 * 13.4164f) + 1;
    int lo = qt * 64 - R;      if (lo < 0) lo = 0;     lo &= ~63;
    int hi = qt * 64 + 64 + R; if (hi > 4096) hi = 4096; hi = (hi + 63) & ~63;

    // fixed-max softmax constants: p = exp2(s*c1 + d2*c2m + c3m)
    const float c1  = 0.125f * LOG2E;
    const float c2m = -cb * LOG2E;
    const float c3m = -12.0f * LOG2E;

    // Q A-operand fragments (m = lane&15, k = quad*8+j, two 32-k chunks)
    const int qrow_f = qt * 64 + wv * 16 + ln;
    const bf16* qptr = Qb + ((size_t)bh * 4096 + qrow_f) * 64 + quad * 8;
    bf16x8 qf0 = *(const bf16x8*)qptr;
    bf16x8 qf1 = *(const bf16x8*)(qptr + 32);

    const int qrow_c = qt * 64 + wv * 16 + quad * 4;   // C-layout row base
    const float fln = (float)ln;

    f32x4 o[4] = {};
    f32x4 lsum = {};
    const bf16 one = (bf16)1.0f;
    const bf16x8 onesv = { one, one, one, one, one, one, one, one };

    const int srow = tid >> 3;            // staging row this thread covers (i=0)
    const int scc  = tid & 7;

    for (int ct = lo; ct < hi; ct += 128) {
        const int ntiles = ((hi - ct) >= 128) ? 2 : 1;
        __syncthreads();   // previous chunk fully consumed
        #pragma unroll
        for (int tt = 0; tt < 2; ++tt) {
            if (tt < ntiles) {
                const bf16* Kg = Kb + ((size_t)bh * 4096 + ct + tt * 64) * 64;
                const bf16* Vg = Vt + (size_t)bh * 64 * 4096 + ct + tt * 64;
                bf16* Ksl = &KVs[tt][0][0];
                bf16* Vsl = &KVs[tt][1][0];
                #pragma unroll
                for (int i = 0; i < 2; ++i) {
                    int c = tid + 256 * i;
                    int row = srow + 32 * i;
                    int cg = scc ^ (row & 7);
                    async16(Kg + row * 64 + cg * 8, Ksl + c * 8);
                    async16(Vg + (size_t)row * 4096 + cg * 8, Vsl + c * 8);
                }
            }
        }
        __syncthreads();   // staging complete (vmcnt drained at barrier)

        for (int tt = 0; tt < ntiles; ++tt) {
            const int kt = ct + tt * 64;
            const bf16* Ks = &KVs[tt][0][0];
            const bf16* Vs = &KVs[tt][1][0];

            // S = Q K^T  (16 q-rows x 64 k-cols)
            f32x4 sc[4] = {};
            #pragma unroll
            for (int tI = 0; tI < 4; ++tI) {
                int row = tI * 16 + ln;
                bf16x8 kf0 = *(const bf16x8*)&Ks[(row * 8 + ((quad    ) ^ (row & 7))) * 8];
                bf16x8 kf1 = *(const bf16x8*)&Ks[(row * 8 + ((4 + quad) ^ (row & 7))) * 8];
                sc[tI] = mfma16(qf0, kf0, sc[tI]);
                sc[tI] = mfma16(qf1, kf1, sc[tI]);
            }

            // fixed-max softmax: p = exp2(s*c1 + d2*c2m + c3m); no reductions
            float p[4][4];
            #pragma unroll
            for (int r = 0; r < 4; ++r) {
                float Ar = (float)(qrow_c + r - kt) - fln;
                #pragma unroll
                for (int tI = 0; tI < 4; ++tI) {
                    float df = Ar - (float)(tI * 16);
                    float lg = fmaf(sc[tI][r], c1, fmaf(df, df * c2m, c3m));
                    p[tI][r] = __builtin_amdgcn_exp2f(lg);
                }
            }

            // P (C-layout) -> LDS -> A-operand layout; wave-private
            #pragma unroll
            for (int tI = 0; tI < 4; ++tI)
                #pragma unroll
                for (int r = 0; r < 4; ++r) {
                    int row = quad * 4 + r;
                    int cc  = tI * 2 + (ln >> 3);
                    int idx = row * 64 + ((cc ^ (row & 7)) * 8) + (ln & 7);
                    Ps[wv][idx] = (bf16)p[tI][r];
                }

            bf16x8 pf[2];
            #pragma unroll
            for (int c = 0; c < 2; ++c)
                pf[c] = *(const bf16x8*)&Ps[wv][(ln * 8 + ((c * 4 + quad) ^ (ln & 7))) * 8];

            // O += P V ; l += P 1  (V^T tile: n=d=lane&15 row, k contiguous)
            #pragma unroll
            for (int c = 0; c < 2; ++c)
                lsum = mfma16(pf[c], onesv, lsum);
            #pragma unroll
            for (int t2 = 0; t2 < 4; ++t2) {
                int vrow = t2 * 16 + ln;
                #pragma unroll
                for (int c = 0; c < 2; ++c) {
                    bf16x8 vf = *(const bf16x8*)&Vs[(vrow * 8 + ((c * 4 + quad) ^ (vrow & 7))) * 8];
                    o[t2] = mfma16(pf[c], vf, o[t2]);
                }
            }
        }
    }

    // epilogue: out[s][h*64+d] = O / l
    float il[4];
    #pragma unroll
    for (int r = 0; r < 4; ++r) il[r] = __builtin_amdgcn_rcpf(lsum[r]);
    #pragma unroll
    for (int t2 = 0; t2 < 4; ++t2) {
        int dd = t2 * 16 + ln;
        #pragma unroll
        for (int r = 0; r < 4; ++r) {
            int s = qt * 64 + wv * 16 + quad * 4 + r;
            AO[((size_t)(b * 4096 + s)) * 512 + h * 64 + dd] = (bf16)(o[t2][r] * il[r]);
        }
    }
}

// ---------------------------------------------------------------------------
// Out projection: OUT[8192][512] = AO[8192][512](bf16) @ W[512][512]^T + bias
// ---------------------------------------------------------------------------
__global__ __launch_bounds__(256) void out_gemm_kernel(
    const bf16* __restrict__ A, const float* __restrict__ W,
    const float* __restrict__ bias, float* __restrict__ OUT)
{
    const int tid  = threadIdx.x;
    const int lane = tid & 63;
    const int wv   = tid >> 6;
    const int quad = lane >> 4;
    const int ln   = lane & 15;
    const int bm   = blockIdx.x;   // 64
    const int bn   = blockIdx.y;   // 4

    __shared__ __align__(16) bf16 As[128 * 64];
    __shared__ __align__(16) bf16 Bs[128 * 64];

    const int wm = (wv >> 1) * 64;
    const int wn = (wv & 1) * 64;

    f32x4 acc[4][4] = {};

    for (int kt = 0; kt < 512; kt += 64) {
        #pragma unroll
        for (int i = 0; i < 4; ++i) {
            int c = tid + 256 * i;
            int row = c >> 3, cc = c & 7;
            uint4 v = *(const uint4*)&A[(size_t)(bm * 128 + row) * 512 + kt + cc * 8];
            *(uint4*)&As[(row * 8 + (cc ^ (row & 7))) * 8] = v;
        }
        #pragma unroll
        for (int i = 0; i < 4; ++i) {
            int c = tid + 256 * i;
            int row = c >> 3, cc = c & 7;
            const float* g = W + (size_t)(bn * 128 + row) * 512 + kt + cc * 8;
            float4 f0 = *(const float4*)g;
            float4 f1 = *(const float4*)(g + 4);
            bf16x8 v = { (bf16)f0.x,(bf16)f0.y,(bf16)f0.z,(bf16)f0.w,
                         (bf16)f1.x,(bf16)f1.y,(bf16)f1.z,(bf16)f1.w };
            *(bf16x8*)&Bs[(row * 8 + (cc ^ (row & 7))) * 8] = v;
        }
        __syncthreads();

        bf16x8 af[4][2], bfr[4][2];
        #pragma unroll
        for (int i = 0; i < 4; ++i) {
            #pragma unroll
            for (int c = 0; c < 2; ++c) {
                int ra = wm + i * 16 + ln;
                af[i][c]  = *(const bf16x8*)&As[(ra * 8 + ((c * 4 + quad) ^ (ra & 7))) * 8];
                int rb = wn + i * 16 + ln;
                bfr[i][c] = *(const bf16x8*)&Bs[(rb * 8 + ((c * 4 + quad) ^ (rb & 7))) * 8];
            }
        }
        #pragma unroll
        for (int c = 0; c < 2; ++c)
            #pragma unroll
            for (int i = 0; i < 4; ++i)
                #pragma unroll
                for (int j = 0; j < 4; ++j)
                    acc[i][j] = mfma16(af[i][c], bfr[j][c], acc[i][j]);
        __syncthreads();
    }

    #pragma unroll
    for (int i = 0; i < 4; ++i) {
        int mbase = bm * 128 + wm + i * 16 + quad * 4;
        #pragma unroll
        for (int j = 0; j < 4; ++j) {
            int n = bn * 128 + wn + j * 16 + ln;
            float bv = bias[n];
            #pragma unroll
            for (int r = 0; r < 4; ++r)
                OUT[(size_t)(mbase + r) * 512 + n] = acc[i][j][r] + bv;
        }
    }
}

extern "C" void kernel_launch(void* const* d_in, const int* in_sizes, int n_in,
                              void* d_out, int out_size, void* d_ws, size_t ws_size,
                              hipStream_t stream)
{
    const float* x  = (const float*)d_in[0];
    const float* wi = (const float*)d_in[1];
    const float* bi = (const float*)d_in[2];
    const float* wo = (const float*)d_in[3];
    const float* bo = (const float*)d_in[4];
    const float* t  = (const float*)d_in[5];
    float* out = (float*)d_out;

    // ws layout: Q, K, V^T, attn_out  — each [16][4096][64] bf16 = 8 MB
    bf16* Qb = (bf16*)d_ws;
    bf16* Kb = Qb + 4194304;
    bf16* Vt = Kb + 4194304;
    bf16* AO = Vt + 4194304;

    qkv_gemm_kernel<<<dim3(64, 12), 256, 0, stream>>>(x, wi, bi, Qb, Kb, Vt);
    attn_kernel   <<<dim3(64, 16), 256, 0, stream>>>(Qb, Kb, Vt, t, AO);
    out_gemm_kernel<<<dim3(64, 4), 256, 0, stream>>>(AO, wo, bo, out);
}

// Round 4
// 128.455 us; speedup vs baseline: 3.3039x; 1.0819x over previous
//
#include <hip/hip_runtime.h>
#include <hip/hip_bf16.h>
#include <stdint.h>

// Problem: B=2, S=4096, E=512, H=8, D=64.  All fp32 in/out; bf16 MFMA inside.
#define LOG2E 1.4426950408889634f

typedef __bf16 bf16;
typedef __bf16 bf16x8 __attribute__((ext_vector_type(8)));
typedef float  f32x4  __attribute__((ext_vector_type(4)));

__device__ __forceinline__ f32x4 mfma16(bf16x8 a, bf16x8 b, f32x4 c) {
    return __builtin_amdgcn_mfma_f32_16x16x32_bf16(a, b, c, 0, 0, 0);
}

__device__ __forceinline__ void async16(const void* g, void* l) {
    __builtin_amdgcn_global_load_lds(
        (const __attribute__((address_space(1))) void*)g,
        (__attribute__((address_space(3))) void*)l, 16, 0, 0);
}

// ---------------------------------------------------------------------------
// Elementwise fp32 -> bf16 convert for X, W_in, W_out (one pass, vectorized).
// N1=8192*512=4194304, N2=1536*512=786432, N3=512*512=262144; all /8.
// ---------------------------------------------------------------------------
__global__ __launch_bounds__(256) void cvt_kernel(
    const float* __restrict__ X, const float* __restrict__ Wi,
    const float* __restrict__ Wo,
    bf16* __restrict__ Xb, bf16* __restrict__ Wib, bf16* __restrict__ Wob)
{
    size_t e = ((size_t)blockIdx.x * 256 + threadIdx.x) * 8;
    const float* src; bf16* dst; size_t off;
    if (e < 4194304)      { src = X;  dst = Xb;  off = e; }
    else if (e < 4980736) { src = Wi; dst = Wib; off = e - 4194304; }
    else                  { src = Wo; dst = Wob; off = e - 4980736; }
    float4 f0 = *(const float4*)(src + off);
    float4 f1 = *(const float4*)(src + off + 4);
    bf16x8 v = { (bf16)f0.x,(bf16)f0.y,(bf16)f0.z,(bf16)f0.w,
                 (bf16)f1.x,(bf16)f1.y,(bf16)f1.z,(bf16)f1.w };
    *(bf16x8*)(dst + off) = v;
}

// ---------------------------------------------------------------------------
// QKV GEMM (bf16): C[8192][1536] = Xb @ Wib^T + bias
// m97 structure: 128x128 tile, BK=64, global_load_lds width=16 staging with
// source-side XOR swizzle (LDS dest contiguous = base + lane*16).
// Epilogue routes: n<512 -> Q[bh][s][d], n<1024 -> K[bh][s][d], else V^T.
// ---------------------------------------------------------------------------
__global__ __launch_bounds__(256) void qkv_gemm_kernel(
    const bf16* __restrict__ Xb, const bf16* __restrict__ Wb,
    const float* __restrict__ bias,
    bf16* __restrict__ Qb, bf16* __restrict__ Kb, bf16* __restrict__ Vt)
{
    const int tid  = threadIdx.x;
    const int lane = tid & 63;
    const int wv   = tid >> 6;
    const int quad = lane >> 4;
    const int ln   = lane & 15;
    const int bm   = blockIdx.x;   // 64
    const int bn   = blockIdx.y;   // 12

    __shared__ __align__(16) bf16 As[128 * 64];
    __shared__ __align__(16) bf16 Bs[128 * 64];

    const int wm = (wv >> 1) * 64;
    const int wn = (wv & 1) * 64;

    const int srow = tid >> 3;   // 0..31
    const int scc  = tid & 7;

    const bf16* XA = Xb + (size_t)bm * 128 * 512;
    const bf16* WB = Wb + (size_t)bn * 128 * 512;

    f32x4 acc[4][4] = {};

    for (int kt = 0; kt < 512; kt += 64) {
        #pragma unroll
        for (int i = 0; i < 4; ++i) {
            int c   = tid + 256 * i;
            int row = srow + 32 * i;
            int cg  = scc ^ (row & 7);
            async16(XA + (size_t)row * 512 + kt + cg * 8, As + c * 8);
            async16(WB + (size_t)row * 512 + kt + cg * 8, Bs + c * 8);
        }
        __syncthreads();   // drains vmcnt

        bf16x8 af[4][2], bfr[4][2];
        #pragma unroll
        for (int i = 0; i < 4; ++i) {
            #pragma unroll
            for (int c = 0; c < 2; ++c) {
                int ra = wm + i * 16 + ln;
                af[i][c]  = *(const bf16x8*)&As[(ra * 8 + ((c * 4 + quad) ^ (ra & 7))) * 8];
                int rb = wn + i * 16 + ln;
                bfr[i][c] = *(const bf16x8*)&Bs[(rb * 8 + ((c * 4 + quad) ^ (rb & 7))) * 8];
            }
        }
        #pragma unroll
        for (int c = 0; c < 2; ++c)
            #pragma unroll
            for (int i = 0; i < 4; ++i)
                #pragma unroll
                for (int j = 0; j < 4; ++j)
                    acc[i][j] = mfma16(af[i][c], bfr[j][c], acc[i][j]);
        __syncthreads();
    }

    #pragma unroll
    for (int i = 0; i < 4; ++i) {
        int mbase = bm * 128 + wm + i * 16 + quad * 4;
        #pragma unroll
        for (int j = 0; j < 4; ++j) {
            int n = bn * 128 + wn + j * 16 + ln;
            float bv = bias[n];
            int sec = n >> 9;
            int e = n & 511;
            int hh = e >> 6, dd = e & 63;
            #pragma unroll
            for (int r = 0; r < 4; ++r) {
                int mm = mbase + r;
                int b = mm >> 12, s = mm & 4095;
                bf16 v = (bf16)(acc[i][j][r] + bv);
                size_t bhi = (size_t)(b * 8 + hh);
                if (sec == 0)      Qb[(bhi * 4096 + s) * 64 + dd] = v;
                else if (sec == 1) Kb[(bhi * 4096 + s) * 64 + dd] = v;
                else               Vt[(bhi * 64 + dd) * 4096 + s] = v;
            }
        }
    }
}

// ---------------------------------------------------------------------------
// Flash attention, BANDED, fixed-max softmax (no rescale), l via ones-MFMA.
// Chunked async staging: 2 k-tiles per chunk via global_load_lds width=16,
// swizzle applied on the GLOBAL source address (LDS dest = base + lane*16).
// Grid: (S/64, B*H). Block: 256 thr = 4 waves; wave w owns q rows w*16..+15.
// ---------------------------------------------------------------------------
__global__ __launch_bounds__(256) void attn_kernel(
    const bf16* __restrict__ Qb, const bf16* __restrict__ Kb,
    const bf16* __restrict__ Vt, const float* __restrict__ T,
    bf16* __restrict__ AO)
{
    const int tid  = threadIdx.x;
    const int lane = tid & 63;
    const int wv   = tid >> 6;
    const int quad = lane >> 4;
    const int ln   = lane & 15;
    const int qt   = blockIdx.x;   // 64
    const int bh   = blockIdx.y;   // 16
    const int h    = bh & 7;
    const int b    = bh >> 3;

    // [tile 0/1][K=0,V=1][64*64]
    __shared__ __align__(16) bf16 KVs[2][2][64 * 64];
    __shared__ __align__(16) bf16 Ps[4][16 * 64];

    const float t  = T[h];
    const float s2 = t * t;
    const float cb = 1.0f / (2.0f * s2 * s2);    // bias = -dist2 * cb

    // band radius: dist^2 * cb >= 90  =>  dist >= t^2 * sqrt(180)
    const int R  = (int)ceilf(s2 * 13.4164f) + 1;
    int lo = qt * 64 - R;      if (lo < 0) lo = 0;     lo &= ~63;
    int hi = qt * 64 + 64 + R; if (hi > 4096) hi = 4096; hi = (hi + 63) & ~63;

    // fixed-max softmax constants: p = exp2(s*c1 + d2*c2m + c3m)
    const float c1  = 0.125f * LOG2E;
    const float c2m = -cb * LOG2E;
    const float c3m = -12.0f * LOG2E;

    // Q A-operand fragments (m = lane&15, k = quad*8+j, two 32-k chunks)
    const int qrow_f = qt * 64 + wv * 16 + ln;
    const bf16* qptr = Qb + ((size_t)bh * 4096 + qrow_f) * 64 + quad * 8;
    bf16x8 qf0 = *(const bf16x8*)qptr;
    bf16x8 qf1 = *(const bf16x8*)(qptr + 32);

    const int qrow_c = qt * 64 + wv * 16 + quad * 4;   // C-layout row base
    const float fln = (float)ln;

    f32x4 o[4] = {};
    f32x4 lsum = {};
    const bf16 one = (bf16)1.0f;
    const bf16x8 onesv = { one, one, one, one, one, one, one, one };

    const int srow = tid >> 3;            // staging row this thread covers (i=0)
    const int scc  = tid & 7;

    for (int ct = lo; ct < hi; ct += 128) {
        const int ntiles = ((hi - ct) >= 128) ? 2 : 1;
        __syncthreads();   // previous chunk fully consumed
        #pragma unroll
        for (int tt = 0; tt < 2; ++tt) {
            if (tt < ntiles) {
                const bf16* Kg = Kb + ((size_t)bh * 4096 + ct + tt * 64) * 64;
                const bf16* Vg = Vt + (size_t)bh * 64 * 4096 + ct + tt * 64;
                bf16* Ksl = &KVs[tt][0][0];
                bf16* Vsl = &KVs[tt][1][0];
                #pragma unroll
                for (int i = 0; i < 2; ++i) {
                    int c = tid + 256 * i;
                    int row = srow + 32 * i;
                    int cg = scc ^ (row & 7);
                    async16(Kg + row * 64 + cg * 8, Ksl + c * 8);
                    async16(Vg + (size_t)row * 4096 + cg * 8, Vsl + c * 8);
                }
            }
        }
        __syncthreads();   // staging complete (vmcnt drained at barrier)

        for (int tt = 0; tt < ntiles; ++tt) {
            const int kt = ct + tt * 64;
            const bf16* Ks = &KVs[tt][0][0];
            const bf16* Vs = &KVs[tt][1][0];

            // S = Q K^T  (16 q-rows x 64 k-cols)
            f32x4 sc[4] = {};
            #pragma unroll
            for (int tI = 0; tI < 4; ++tI) {
                int row = tI * 16 + ln;
                bf16x8 kf0 = *(const bf16x8*)&Ks[(row * 8 + ((quad    ) ^ (row & 7))) * 8];
                bf16x8 kf1 = *(const bf16x8*)&Ks[(row * 8 + ((4 + quad) ^ (row & 7))) * 8];
                sc[tI] = mfma16(qf0, kf0, sc[tI]);
                sc[tI] = mfma16(qf1, kf1, sc[tI]);
            }

            // fixed-max softmax: p = exp2(s*c1 + d2*c2m + c3m); no reductions
            float p[4][4];
            #pragma unroll
            for (int r = 0; r < 4; ++r) {
                float Ar = (float)(qrow_c + r - kt) - fln;
                #pragma unroll
                for (int tI = 0; tI < 4; ++tI) {
                    float df = Ar - (float)(tI * 16);
                    float lg = fmaf(sc[tI][r], c1, fmaf(df, df * c2m, c3m));
                    p[tI][r] = __builtin_amdgcn_exp2f(lg);
                }
            }

            // P (C-layout) -> LDS -> A-operand layout; wave-private
            #pragma unroll
            for (int tI = 0; tI < 4; ++tI)
                #pragma unroll
                for (int r = 0; r < 4; ++r) {
                    int row = quad * 4 + r;
                    int cc  = tI * 2 + (ln >> 3);
                    int idx = row * 64 + ((cc ^ (row & 7)) * 8) + (ln & 7);
                    Ps[wv][idx] = (bf16)p[tI][r];
                }

            bf16x8 pf[2];
            #pragma unroll
            for (int c = 0; c < 2; ++c)
                pf[c] = *(const bf16x8*)&Ps[wv][(ln * 8 + ((c * 4 + quad) ^ (ln & 7))) * 8];

            // O += P V ; l += P 1  (V^T tile: n=d=lane&15 row, k contiguous)
            #pragma unroll
            for (int c = 0; c < 2; ++c)
                lsum = mfma16(pf[c], onesv, lsum);
            #pragma unroll
            for (int t2 = 0; t2 < 4; ++t2) {
                int vrow = t2 * 16 + ln;
                #pragma unroll
                for (int c = 0; c < 2; ++c) {
                    bf16x8 vf = *(const bf16x8*)&Vs[(vrow * 8 + ((c * 4 + quad) ^ (vrow & 7))) * 8];
                    o[t2] = mfma16(pf[c], vf, o[t2]);
                }
            }
        }
    }

    // epilogue: out[s][h*64+d] = O / l
    float il[4];
    #pragma unroll
    for (int r = 0; r < 4; ++r) il[r] = __builtin_amdgcn_rcpf(lsum[r]);
    #pragma unroll
    for (int t2 = 0; t2 < 4; ++t2) {
        int dd = t2 * 16 + ln;
        #pragma unroll
        for (int r = 0; r < 4; ++r) {
            int s = qt * 64 + wv * 16 + quad * 4 + r;
            AO[((size_t)(b * 4096 + s)) * 512 + h * 64 + dd] = (bf16)(o[t2][r] * il[r]);
        }
    }
}

// ---------------------------------------------------------------------------
// Out projection (bf16): OUT[8192][512] = AO @ Wob^T + bias (fp32 out)
// Same m97 structure as qkv_gemm.
// ---------------------------------------------------------------------------
__global__ __launch_bounds__(256) void out_gemm_kernel(
    const bf16* __restrict__ A, const bf16* __restrict__ Wb,
    const float* __restrict__ bias, float* __restrict__ OUT)
{
    const int tid  = threadIdx.x;
    const int lane = tid & 63;
    const int wv   = tid >> 6;
    const int quad = lane >> 4;
    const int ln   = lane & 15;
    const int bm   = blockIdx.x;   // 64
    const int bn   = blockIdx.y;   // 4

    __shared__ __align__(16) bf16 As[128 * 64];
    __shared__ __align__(16) bf16 Bs[128 * 64];

    const int wm = (wv >> 1) * 64;
    const int wn = (wv & 1) * 64;

    const int srow = tid >> 3;
    const int scc  = tid & 7;

    const bf16* AA = A  + (size_t)bm * 128 * 512;
    const bf16* WB = Wb + (size_t)bn * 128 * 512;

    f32x4 acc[4][4] = {};

    for (int kt = 0; kt < 512; kt += 64) {
        #pragma unroll
        for (int i = 0; i < 4; ++i) {
            int c   = tid + 256 * i;
            int row = srow + 32 * i;
            int cg  = scc ^ (row & 7);
            async16(AA + (size_t)row * 512 + kt + cg * 8, As + c * 8);
            async16(WB + (size_t)row * 512 + kt + cg * 8, Bs + c * 8);
        }
        __syncthreads();

        bf16x8 af[4][2], bfr[4][2];
        #pragma unroll
        for (int i = 0; i < 4; ++i) {
            #pragma unroll
            for (int c = 0; c < 2; ++c) {
                int ra = wm + i * 16 + ln;
                af[i][c]  = *(const bf16x8*)&As[(ra * 8 + ((c * 4 + quad) ^ (ra & 7))) * 8];
                int rb = wn + i * 16 + ln;
                bfr[i][c] = *(const bf16x8*)&Bs[(rb * 8 + ((c * 4 + quad) ^ (rb & 7))) * 8];
            }
        }
        #pragma unroll
        for (int c = 0; c < 2; ++c)
            #pragma unroll
            for (int i = 0; i < 4; ++i)
                #pragma unroll
                for (int j = 0; j < 4; ++j)
                    acc[i][j] = mfma16(af[i][c], bfr[j][c], acc[i][j]);
        __syncthreads();
    }

    #pragma unroll
    for (int i = 0; i < 4; ++i) {
        int mbase = bm * 128 + wm + i * 16 + quad * 4;
        #pragma unroll
        for (int j = 0; j < 4; ++j) {
            int n = bn * 128 + wn + j * 16 + ln;
            float bv = bias[n];
            #pragma unroll
            for (int r = 0; r < 4; ++r)
                OUT[(size_t)(mbase + r) * 512 + n] = acc[i][j][r] + bv;
        }
    }
}

extern "C" void kernel_launch(void* const* d_in, const int* in_sizes, int n_in,
                              void* d_out, int out_size, void* d_ws, size_t ws_size,
                              hipStream_t stream)
{
    const float* x  = (const float*)d_in[0];
    const float* wi = (const float*)d_in[1];
    const float* bi = (const float*)d_in[2];
    const float* wo = (const float*)d_in[3];
    const float* bo = (const float*)d_in[4];
    const float* t  = (const float*)d_in[5];
    float* out = (float*)d_out;

    // ws layout (bf16 elements):
    bf16* Qb  = (bf16*)d_ws;          // 4194304
    bf16* Kb  = Qb  + 4194304;        // 4194304
    bf16* Vt  = Kb  + 4194304;        // 4194304
    bf16* AO  = Vt  + 4194304;        // 4194304
    bf16* Xb  = AO  + 4194304;        // 4194304
    bf16* Wib = Xb  + 4194304;        // 786432
    bf16* Wob = Wib + 786432;         // 262144

    cvt_kernel     <<<dim3(2560), 256, 0, stream>>>(x, wi, wo, Xb, Wib, Wob);
    qkv_gemm_kernel<<<dim3(64, 12), 256, 0, stream>>>(Xb, Wib, bi, Qb, Kb, Vt);
    attn_kernel    <<<dim3(64, 16), 256, 0, stream>>>(Qb, Kb, Vt, t, AO);
    out_gemm_kernel<<<dim3(64, 4), 256, 0, stream>>>(AO, Wob, bo, out);
}

// Round 6
// 126.305 us; speedup vs baseline: 3.3602x; 1.0170x over previous
//
#include <hip/hip_runtime.h>
#include <hip/hip_bf16.h>
#include <stdint.h>

// Problem: B=2, S=4096, E=512, H=8, D=64.  All fp32 in/out; bf16 MFMA inside.
#define LOG2E 1.4426950408889634f

typedef __bf16 bf16;
typedef __bf16 bf16x8 __attribute__((ext_vector_type(8)));
typedef float  f32x4  __attribute__((ext_vector_type(4)));

__device__ __forceinline__ f32x4 mfma16(bf16x8 a, bf16x8 b, f32x4 c) {
    return __builtin_amdgcn_mfma_f32_16x16x32_bf16(a, b, c, 0, 0, 0);
}

__device__ __forceinline__ void async16(const void* g, void* l) {
    __builtin_amdgcn_global_load_lds(
        (const __attribute__((address_space(1))) void*)g,
        (__attribute__((address_space(3))) void*)l, 16, 0, 0);
}

// ---------------------------------------------------------------------------
// Elementwise fp32 -> bf16 convert for X, W_in, W_out (one pass, vectorized).
// ---------------------------------------------------------------------------
__global__ __launch_bounds__(256) void cvt_kernel(
    const float* __restrict__ X, const float* __restrict__ Wi,
    const float* __restrict__ Wo,
    bf16* __restrict__ Xb, bf16* __restrict__ Wib, bf16* __restrict__ Wob)
{
    size_t e = ((size_t)blockIdx.x * 256 + threadIdx.x) * 8;
    const float* src; bf16* dst; size_t off;
    if (e < 4194304)      { src = X;  dst = Xb;  off = e; }
    else if (e < 4980736) { src = Wi; dst = Wib; off = e - 4194304; }
    else                  { src = Wo; dst = Wob; off = e - 4980736; }
    float4 f0 = *(const float4*)(src + off);
    float4 f1 = *(const float4*)(src + off + 4);
    bf16x8 v = { (bf16)f0.x,(bf16)f0.y,(bf16)f0.z,(bf16)f0.w,
                 (bf16)f1.x,(bf16)f1.y,(bf16)f1.z,(bf16)f1.w };
    *(bf16x8*)(dst + off) = v;
}

// ---------------------------------------------------------------------------
// QKV GEMM (bf16): C[8192][1536] = Xb @ Wib^T + bias
// m97 structure: 128x128 tile, BK=64, global_load_lds width=16 staging with
// source-side XOR swizzle (LDS dest contiguous = base + lane*16).
// Epilogue routes: n<512 -> Q[bh][s][d], n<1024 -> K[bh][s][d], else V^T.
// ---------------------------------------------------------------------------
__global__ __launch_bounds__(256) void qkv_gemm_kernel(
    const bf16* __restrict__ Xb, const bf16* __restrict__ Wb,
    const float* __restrict__ bias,
    bf16* __restrict__ Qb, bf16* __restrict__ Kb, bf16* __restrict__ Vt)
{
    const int tid  = threadIdx.x;
    const int lane = tid & 63;
    const int wv   = tid >> 6;
    const int quad = lane >> 4;
    const int ln   = lane & 15;
    const int bm   = blockIdx.x;   // 64
    const int bn   = blockIdx.y;   // 12

    __shared__ __align__(16) bf16 As[128 * 64];
    __shared__ __align__(16) bf16 Bs[128 * 64];

    const int wm = (wv >> 1) * 64;
    const int wn = (wv & 1) * 64;

    const int srow = tid >> 3;   // 0..31
    const int scc  = tid & 7;

    const bf16* XA = Xb + (size_t)bm * 128 * 512;
    const bf16* WB = Wb + (size_t)bn * 128 * 512;

    f32x4 acc[4][4] = {};

    for (int kt = 0; kt < 512; kt += 64) {
        #pragma unroll
        for (int i = 0; i < 4; ++i) {
            int c   = tid + 256 * i;
            int row = srow + 32 * i;
            int cg  = scc ^ (row & 7);
            async16(XA + (size_t)row * 512 + kt + cg * 8, As + c * 8);
            async16(WB + (size_t)row * 512 + kt + cg * 8, Bs + c * 8);
        }
        __syncthreads();   // drains vmcnt

        bf16x8 af[4][2], bfr[4][2];
        #pragma unroll
        for (int i = 0; i < 4; ++i) {
            #pragma unroll
            for (int c = 0; c < 2; ++c) {
                int ra = wm + i * 16 + ln;
                af[i][c]  = *(const bf16x8*)&As[(ra * 8 + ((c * 4 + quad) ^ (ra & 7))) * 8];
                int rb = wn + i * 16 + ln;
                bfr[i][c] = *(const bf16x8*)&Bs[(rb * 8 + ((c * 4 + quad) ^ (rb & 7))) * 8];
            }
        }
        #pragma unroll
        for (int c = 0; c < 2; ++c)
            #pragma unroll
            for (int i = 0; i < 4; ++i)
                #pragma unroll
                for (int j = 0; j < 4; ++j)
                    acc[i][j] = mfma16(af[i][c], bfr[j][c], acc[i][j]);
        __syncthreads();
    }

    #pragma unroll
    for (int i = 0; i < 4; ++i) {
        int mbase = bm * 128 + wm + i * 16 + quad * 4;
        #pragma unroll
        for (int j = 0; j < 4; ++j) {
            int n = bn * 128 + wn + j * 16 + ln;
            float bv = bias[n];
            int sec = n >> 9;
            int e = n & 511;
            int hh = e >> 6, dd = e & 63;
            #pragma unroll
            for (int r = 0; r < 4; ++r) {
                int mm = mbase + r;
                int b = mm >> 12, s = mm & 4095;
                bf16 v = (bf16)(acc[i][j][r] + bv);
                size_t bhi = (size_t)(b * 8 + hh);
                if (sec == 0)      Qb[(bhi * 4096 + s) * 64 + dd] = v;
                else if (sec == 1) Kb[(bhi * 4096 + s) * 64 + dd] = v;
                else               Vt[(bhi * 64 + dd) * 4096 + s] = v;
            }
        }
    }
}

// ---------------------------------------------------------------------------
// Flash attention, BANDED (R = 8*t^2), fixed-max softmax (no rescale),
// l via ones-MFMA.  EXACT round-4 structure (validated through timed
// replays); only the band constant changed (13.4164 -> 8.0, margin 32).
// Grid: (S/64, B*H). Block: 256 thr = 4 waves; wave w owns q rows w*16..+15.
// ---------------------------------------------------------------------------
__global__ __launch_bounds__(256) void attn_kernel(
    const bf16* __restrict__ Qb, const bf16* __restrict__ Kb,
    const bf16* __restrict__ Vt, const float* __restrict__ T,
    bf16* __restrict__ AO)
{
    const int tid  = threadIdx.x;
    const int lane = tid & 63;
    const int wv   = tid >> 6;
    const int quad = lane >> 4;
    const int ln   = lane & 15;
    const int qt   = blockIdx.x;   // 64
    const int bh   = blockIdx.y;   // 16
    const int h    = bh & 7;
    const int b    = bh >> 3;

    // [tile 0/1][K=0,V=1][64*64]
    __shared__ __align__(16) bf16 KVs[2][2][64 * 64];
    __shared__ __align__(16) bf16 Ps[4][16 * 64];

    const float t  = T[h];
    const float s2 = t * t;
    const float cb = 1.0f / (2.0f * s2 * s2);    // bias = -dist2 * cb

    // band radius: dist^2 * cb >= 32  =>  dist >= t^2 * 8
    const int R  = (int)ceilf(s2 * 8.0f) + 1;
    int lo = qt * 64 - R;      if (lo < 0) lo = 0;     lo &= ~63;
    int hi = qt * 64 + 64 + R; if (hi > 4096) hi = 4096; hi = (hi + 63) & ~63;

    // fixed-max softmax constants: p = exp2(s*c1 + d2*c2m + c3m)
    const float c1  = 0.125f * LOG2E;
    const float c2m = -cb * LOG2E;
    const float c3m = -12.0f * LOG2E;

    // Q A-operand fragments (m = lane&15, k = quad*8+j, two 32-k chunks)
    const int qrow_f = qt * 64 + wv * 16 + ln;
    const bf16* qptr = Qb + ((size_t)bh * 4096 + qrow_f) * 64 + quad * 8;
    bf16x8 qf0 = *(const bf16x8*)qptr;
    bf16x8 qf1 = *(const bf16x8*)(qptr + 32);

    const int qrow_c = qt * 64 + wv * 16 + quad * 4;   // C-layout row base
    const float fln = (float)ln;

    f32x4 o[4] = {};
    f32x4 lsum = {};
    const bf16 one = (bf16)1.0f;
    const bf16x8 onesv = { one, one, one, one, one, one, one, one };

    const int srow = tid >> 3;            // staging row this thread covers (i=0)
    const int scc  = tid & 7;

    for (int ct = lo; ct < hi; ct += 128) {
        const int ntiles = ((hi - ct) >= 128) ? 2 : 1;
        __syncthreads();   // previous chunk fully consumed
        #pragma unroll
        for (int tt = 0; tt < 2; ++tt) {
            if (tt < ntiles) {
                const bf16* Kg = Kb + ((size_t)bh * 4096 + ct + tt * 64) * 64;
                const bf16* Vg = Vt + (size_t)bh * 64 * 4096 + ct + tt * 64;
                bf16* Ksl = &KVs[tt][0][0];
                bf16* Vsl = &KVs[tt][1][0];
                #pragma unroll
                for (int i = 0; i < 2; ++i) {
                    int c = tid + 256 * i;
                    int row = srow + 32 * i;
                    int cg = scc ^ (row & 7);
                    async16(Kg + row * 64 + cg * 8, Ksl + c * 8);
                    async16(Vg + (size_t)row * 4096 + cg * 8, Vsl + c * 8);
                }
            }
        }
        __syncthreads();   // staging complete (vmcnt drained at barrier)

        for (int tt = 0; tt < ntiles; ++tt) {
            const int kt = ct + tt * 64;
            const bf16* Ks = &KVs[tt][0][0];
            const bf16* Vs = &KVs[tt][1][0];

            // S = Q K^T  (16 q-rows x 64 k-cols)
            f32x4 sc[4] = {};
            #pragma unroll
            for (int tI = 0; tI < 4; ++tI) {
                int row = tI * 16 + ln;
                bf16x8 kf0 = *(const bf16x8*)&Ks[(row * 8 + ((quad    ) ^ (row & 7))) * 8];
                bf16x8 kf1 = *(const bf16x8*)&Ks[(row * 8 + ((4 + quad) ^ (row & 7))) * 8];
                sc[tI] = mfma16(qf0, kf0, sc[tI]);
                sc[tI] = mfma16(qf1, kf1, sc[tI]);
            }

            // fixed-max softmax: p = exp2(s*c1 + d2*c2m + c3m); no reductions
            float p[4][4];
            #pragma unroll
            for (int r = 0; r < 4; ++r) {
                float Ar = (float)(qrow_c + r - kt) - fln;
                #pragma unroll
                for (int tI = 0; tI < 4; ++tI) {
                    float df = Ar - (float)(tI * 16);
                    float lg = fmaf(sc[tI][r], c1, fmaf(df, df * c2m, c3m));
                    p[tI][r] = __builtin_amdgcn_exp2f(lg);
                }
            }

            // P (C-layout) -> LDS -> A-operand layout; wave-private
            #pragma unroll
            for (int tI = 0; tI < 4; ++tI)
                #pragma unroll
                for (int r = 0; r < 4; ++r) {
                    int row = quad * 4 + r;
                    int cc  = tI * 2 + (ln >> 3);
                    int idx = row * 64 + ((cc ^ (row & 7)) * 8) + (ln & 7);
                    Ps[wv][idx] = (bf16)p[tI][r];
                }

            bf16x8 pf[2];
            #pragma unroll
            for (int c = 0; c < 2; ++c)
                pf[c] = *(const bf16x8*)&Ps[wv][(ln * 8 + ((c * 4 + quad) ^ (ln & 7))) * 8];

            // O += P V ; l += P 1  (V^T tile: n=d=lane&15 row, k contiguous)
            #pragma unroll
            for (int c = 0; c < 2; ++c)
                lsum = mfma16(pf[c], onesv, lsum);
            #pragma unroll
            for (int t2 = 0; t2 < 4; ++t2) {
                int vrow = t2 * 16 + ln;
                #pragma unroll
                for (int c = 0; c < 2; ++c) {
                    bf16x8 vf = *(const bf16x8*)&Vs[(vrow * 8 + ((c * 4 + quad) ^ (vrow & 7))) * 8];
                    o[t2] = mfma16(pf[c], vf, o[t2]);
                }
            }
        }
    }

    // epilogue: out[s][h*64+d] = O / l
    float il[4];
    #pragma unroll
    for (int r = 0; r < 4; ++r) il[r] = __builtin_amdgcn_rcpf(lsum[r]);
    #pragma unroll
    for (int t2 = 0; t2 < 4; ++t2) {
        int dd = t2 * 16 + ln;
        #pragma unroll
        for (int r = 0; r < 4; ++r) {
            int s = qt * 64 + wv * 16 + quad * 4 + r;
            AO[((size_t)(b * 4096 + s)) * 512 + h * 64 + dd] = (bf16)(o[t2][r] * il[r]);
        }
    }
}

// ---------------------------------------------------------------------------
// Out projection (bf16): OUT[8192][512] = AO @ Wob^T + bias (fp32 out)
// Same m97 structure as qkv_gemm.
// ---------------------------------------------------------------------------
__global__ __launch_bounds__(256) void out_gemm_kernel(
    const bf16* __restrict__ A, const bf16* __restrict__ Wb,
    const float* __restrict__ bias, float* __restrict__ OUT)
{
    const int tid  = threadIdx.x;
    const int lane = tid & 63;
    const int wv   = tid >> 6;
    const int quad = lane >> 4;
    const int ln   = lane & 15;
    const int bm   = blockIdx.x;   // 64
    const int bn   = blockIdx.y;   // 4

    __shared__ __align__(16) bf16 As[128 * 64];
    __shared__ __align__(16) bf16 Bs[128 * 64];

    const int wm = (wv >> 1) * 64;
    const int wn = (wv & 1) * 64;

    const int srow = tid >> 3;
    const int scc  = tid & 7;

    const bf16* AA = A  + (size_t)bm * 128 * 512;
    const bf16* WB = Wb + (size_t)bn * 128 * 512;

    f32x4 acc[4][4] = {};

    for (int kt = 0; kt < 512; kt += 64) {
        #pragma unroll
        for (int i = 0; i < 4; ++i) {
            int c   = tid + 256 * i;
            int row = srow + 32 * i;
            int cg  = scc ^ (row & 7);
            async16(AA + (size_t)row * 512 + kt + cg * 8, As + c * 8);
            async16(WB + (size_t)row * 512 + kt + cg * 8, Bs + c * 8);
        }
        __syncthreads();

        bf16x8 af[4][2], bfr[4][2];
        #pragma unroll
        for (int i = 0; i < 4; ++i) {
            #pragma unroll
            for (int c = 0; c < 2; ++c) {
                int ra = wm + i * 16 + ln;
                af[i][c]  = *(const bf16x8*)&As[(ra * 8 + ((c * 4 + quad) ^ (ra & 7))) * 8];
                int rb = wn + i * 16 + ln;
                bfr[i][c] = *(const bf16x8*)&Bs[(rb * 8 + ((c * 4 + quad) ^ (rb & 7))) * 8];
            }
        }
        #pragma unroll
        for (int c = 0; c < 2; ++c)
            #pragma unroll
            for (int i = 0; i < 4; ++i)
                #pragma unroll
                for (int j = 0; j < 4; ++j)
                    acc[i][j] = mfma16(af[i][c], bfr[j][c], acc[i][j]);
        __syncthreads();
    }

    #pragma unroll
    for (int i = 0; i < 4; ++i) {
        int mbase = bm * 128 + wm + i * 16 + quad * 4;
        #pragma unroll
        for (int j = 0; j < 4; ++j) {
            int n = bn * 128 + wn + j * 16 + ln;
            float bv = bias[n];
            #pragma unroll
            for (int r = 0; r < 4; ++r)
                OUT[(size_t)(mbase + r) * 512 + n] = acc[i][j][r] + bv;
        }
    }
}

extern "C" void kernel_launch(void* const* d_in, const int* in_sizes, int n_in,
                              void* d_out, int out_size, void* d_ws, size_t ws_size,
                              hipStream_t stream)
{
    const float* x  = (const float*)d_in[0];
    const float* wi = (const float*)d_in[1];
    const float* bi = (const float*)d_in[2];
    const float* wo = (const float*)d_in[3];
    const float* bo = (const float*)d_in[4];
    const float* t  = (const float*)d_in[5];
    float* out = (float*)d_out;

    // ws layout (bf16 elements):
    bf16* Qb  = (bf16*)d_ws;          // 4194304
    bf16* Kb  = Qb  + 4194304;        // 4194304
    bf16* Vt  = Kb  + 4194304;        // 4194304
    bf16* AO  = Vt  + 4194304;        // 4194304
    bf16* Xb  = AO  + 4194304;        // 4194304
    bf16* Wib = Xb  + 4194304;        // 786432
    bf16* Wob = Wib + 786432;         // 262144

    cvt_kernel     <<<dim3(2560), 256, 0, stream>>>(x, wi, wo, Xb, Wib, Wob);
    qkv_gemm_kernel<<<dim3(64, 12), 256, 0, stream>>>(Xb, Wib, bi, Qb, Kb, Vt);
    attn_kernel    <<<dim3(64, 16), 256, 0, stream>>>(Qb, Kb, Vt, t, AO);
    out_gemm_kernel<<<dim3(64, 4), 256, 0, stream>>>(AO, Wob, bo, out);
}